// Round 12
// baseline (227.028 us; speedup 1.0000x reference)
//
#include <hip/hip_runtime.h>
#include <hip/hip_bf16.h>
#include <cstdint>

typedef float f32x4 __attribute__((ext_vector_type(4)));
typedef short bf16x8 __attribute__((ext_vector_type(8)));
typedef short short8 __attribute__((ext_vector_type(8)));

#define CIN   128
#define WIMG  56
#define HWSZ  3136      // 56*56
#define OCH   256
#define HP    58
#define WP    58

// ---- prep A: border-zero (456 blocks) + weight repack (1152 blocks), merged ----
__global__ void small_prep(const float* __restrict__ wsrc,
                           __hip_bfloat16* __restrict__ wb,
                           __hip_bfloat16* __restrict__ xb) {
    int bidx = blockIdx.x;
    if (bidx < 456) {
        int idx = bidx * 256 + threadIdx.x;   // 116736 = 32*228*16
        int c8  = idx & 15;
        int t   = idx >> 4;
        int b   = t / 228;
        int pos = t - b * 228;
        int h, w;
        if (pos < 58)       { h = 0;             w = pos; }
        else if (pos < 116) { h = 57;            w = pos - 58; }
        else if (pos < 172) { h = pos - 116 + 1; w = 0; }
        else                { h = pos - 172 + 1; w = 57; }
        uint4 z = {0, 0, 0, 0};
        *(uint4*)((char*)xb + (((size_t)(b * HP + h) * WP + w) * CIN + c8 * 8) * 2) = z;
    } else {
        int idx = (bidx - 456) * 256 + threadIdx.x;   // 294912 = 9*256*128
        int c    = idx & 127;
        int rest = idx >> 7;
        int o    = rest & 255;
        int ij   = rest >> 8;
        wb[idx] = __float2bfloat16(wsrc[((size_t)o * CIN + c) * 9 + ij]);
    }
}

// ---- prep B: x [B][C][H][W] f32 -> xb padded NHWC bf16 [B][58][58][128] ----
__global__ __launch_bounds__(256)
void cast_transpose_x(const float* __restrict__ x,
                      __hip_bfloat16* __restrict__ xb) {
    __shared__ float tile[64][33];
    const int hw0 = blockIdx.x * 32;
    const int c0  = blockIdx.y * 64;
    const int b   = blockIdx.z;

    const int lx = threadIdx.x & 31;
    const int lc = threadIdx.x >> 5;
    const float* src = x + ((size_t)(b * CIN + c0 + lc) * HWSZ) + hw0 + lx;
#pragma unroll
    for (int k = 0; k < 8; ++k)
        tile[lc + k * 8][lx] = src[(size_t)(k * 8) * HWSZ];
    __syncthreads();

    const int slot = threadIdx.x & 7;
    const int hwl  = threadIdx.x >> 3;
    int hw = hw0 + hwl;
    int h = hw / WIMG;
    int w = hw - h * WIMG;
    short8 v;
#pragma unroll
    for (int j = 0; j < 8; ++j) {
        __hip_bfloat16 hb = __float2bfloat16(tile[slot * 8 + j][hwl]);
        v[j] = *reinterpret_cast<short*>(&hb);
    }
    *(short8*)(xb + (((size_t)b * HP + (h + 1)) * WP + (w + 1)) * CIN + c0 + slot * 8) = v;
}

// ---- main: ZERO-LDS, ZERO-BARRIER direct-register implicit GEMM ----
// BM=128, BN=256, 4 waves (1M x 4N), wave tile 128x64, acc [8][4].
// A and B fragments loaded global->VGPR per lane; per-XCD A working set
// (27.5MB/8 = 3.4MB via swizzle) fits the 4MB L2; B (0.59MB) L1/L2-hot.
// E/O ping-pong: chunk s+1 loads issue before chunk s MFMAs (64-MFMA cover).
// Waves fully independent; compiler + cross-wave TLP hide all latency.
__global__ __launch_bounds__(256, 2)
void conv_gemm(const __hip_bfloat16* __restrict__ xb,
               const __hip_bfloat16* __restrict__ wb,
               const float* __restrict__ bias,
               float* __restrict__ out) {
    const int tid = threadIdx.x;
    const int wn  = tid >> 6;                 // wave = N-slice [wn*64, +64)
    const int ln  = tid & 63;

    int bid = blockIdx.x;
    bid = (bid & 7) * 98 + (bid >> 3);        // XCD swizzle: 784 = 8*98, bijective
    const int m0 = bid * 128;

    const int fr = ln & 15;                   // A row / B col within fragment
    const int ks = ln >> 4;                   // k-slot (8 elems)

    // per-lane A offsets: pixel p = m0 + mi*16 + fr  (verified mapping)
    int aOffL[8];
#pragma unroll
    for (int mi = 0; mi < 8; ++mi) {
        int p  = m0 + mi * 16 + fr;
        int b  = p / HWSZ;
        int hw = p - b * HWSZ;
        int h  = hw / WIMG;
        int w  = hw - h * WIMG;
        aOffL[mi] = ((b * HP + h) * WP + w) * CIN + ks * 8;
    }
    // per-lane B offsets (R7-verified mapping)
    int bOffL[4];
#pragma unroll
    for (int ni = 0; ni < 4; ++ni)
        bOffL[ni] = (wn * 64 + ni * 16 + fr) * CIN + ks * 8;

    f32x4 acc[8][4] = {};
    bf16x8 afE[8], bfE[4], afO[8], bfO[4];

#define LOADF(af, bf, offA, offB) do {                                        \
    _Pragma("unroll") for (int mi = 0; mi < 8; ++mi)                          \
        af[mi] = *(const bf16x8*)(xb + aOffL[mi] + (offA));                   \
    _Pragma("unroll") for (int ni = 0; ni < 4; ++ni)                          \
        bf[ni] = *(const bf16x8*)(wb + bOffL[ni] + (offB));                   \
} while (0)

#define MM32(af, bf) do {                                                     \
    _Pragma("unroll") for (int mi = 0; mi < 8; ++mi)                          \
    _Pragma("unroll") for (int ni = 0; ni < 4; ++ni)                          \
        acc[mi][ni] = __builtin_amdgcn_mfma_f32_16x16x32_bf16(                \
            af[mi], bf[ni], acc[mi][ni], 0, 0, 0);                            \
} while (0)

    // chunk c (c=0..35): tap ij=c>>2, k-sub = (c&3)*32 elems within tap
    // (split each 64-ch chunk into its two kk halves as separate load/MFMA units)
    // E/O ping-pong over 36 half-chunks of K=32.
    LOADF(afE, bfE, 0, 0);                    // half-chunk 0 (tap 0, k 0)

#pragma unroll 1
    for (int i = 0; i < 18; ++i) {
        // half-chunks 2i (E) and 2i+1 (O); prefetch 2i+1 then 2i+2
        const int c1  = 2 * i + 1;
        const int ij1 = c1 >> 2;
        const int ii1 = ij1 / 3, jj1 = ij1 - 3 * ii1;
        const int offA1 = (ii1 * WP + jj1) * CIN + (c1 & 3) * 32;
        const int offB1 = ij1 * (OCH * CIN) + (c1 & 3) * 32;
        LOADF(afO, bfO, offA1, offB1);

        MM32(afE, bfE);                       // compute 2i while 2i+1 in flight

        if (i < 17) {
            const int c2  = 2 * i + 2;
            const int ij2 = c2 >> 2;
            const int ii2 = ij2 / 3, jj2 = ij2 - 3 * ii2;
            const int offA2 = (ii2 * WP + jj2) * CIN + (c2 & 3) * 32;
            const int offB2 = ij2 * (OCH * CIN) + (c2 & 3) * 32;
            LOADF(afE, bfE, offA2, offB2);
        }

        MM32(afO, bfO);                       // compute 2i+1 while 2i+2 in flight
    }
#undef LOADF
#undef MM32

    // ---- epilogue: C/D map col=ln&15 (n), row=(ln>>4)*4+reg (pixel) ----
    const int laneR4 = (ln >> 4) * 4;
    float bn[4];
#pragma unroll
    for (int ni = 0; ni < 4; ++ni)
        bn[ni] = bias[wn * 64 + ni * 16 + fr];

#pragma unroll
    for (int mi = 0; mi < 8; ++mi) {
        int p0 = m0 + mi * 16 + laneR4;       // multiple of 4; 4 | HWSZ
        int b  = p0 / HWSZ;
        int hw = p0 - b * HWSZ;
#pragma unroll
        for (int ni = 0; ni < 4; ++ni) {
            int n = wn * 64 + ni * 16 + fr;
            float4 v;
            v.x = acc[mi][ni][0] + bn[ni];
            v.y = acc[mi][ni][1] + bn[ni];
            v.z = acc[mi][ni][2] + bn[ni];
            v.w = acc[mi][ni][3] + bn[ni];
            *(float4*)(out + ((size_t)(b * OCH + n) * HWSZ + hw)) = v;
        }
    }
}

extern "C" void kernel_launch(void* const* d_in, const int* in_sizes, int n_in,
                              void* d_out, int out_size, void* d_ws, size_t ws_size,
                              hipStream_t stream) {
    const float* x    = (const float*)d_in[0];
    const float* w    = (const float*)d_in[1];
    const float* bias = (const float*)d_in[2];
    float* out = (float*)d_out;

    char* ws = (char*)d_ws;
    __hip_bfloat16* xbuf = (__hip_bfloat16*)ws;                   // 27,557,888 B
    __hip_bfloat16* wbuf = (__hip_bfloat16*)(ws + 27557888);      //    589,824 B

    small_prep<<<1608, 256, 0, stream>>>(w, wbuf, xbuf);
    cast_transpose_x<<<dim3(98, 2, 32), dim3(256), 0, stream>>>(x, xbuf);
    conv_gemm<<<784, 256, 0, stream>>>(xbuf, wbuf, bias, out);
}